// Round 10
// baseline (128.797 us; speedup 1.0000x reference)
//
#include <hip/hip_runtime.h>

#define KS    7
#define H     256
#define W     256
#define STRIP 64                 // output rows per wave
#define WPB   4                  // waves per block (block covers whole plane)
#define NSTEP (STRIP + KS - 1)   // 70 input rows per strip

typedef float vf4 __attribute__((ext_vector_type(4)));

// lane i <- lane i-1 (lane 0 -> 0): wave_shr:1, bound_ctrl=1
__device__ __forceinline__ float dpp_shr1(float x) {
    return __int_as_float(__builtin_amdgcn_mov_dpp(__float_as_int(x), 0x138, 0xf, 0xf, true));
}
// lane i <- lane i+1 (lane 63 -> 0): wave_shl:1, bound_ctrl=1
__device__ __forceinline__ float dpp_shl1(float x) {
    return __int_as_float(__builtin_amdgcn_mov_dpp(__float_as_int(x), 0x130, 0xf, 0xf, true));
}

// Build effective 7x7 kernel: w_eff = mk + noise*(noise_eps - mean(noise_eps))
__global__ void GaussianConvBlur_wprep(const float* __restrict__ weight,
                                       const float* __restrict__ noise,
                                       const float* __restrict__ noise_eps,
                                       float* __restrict__ wf) {
    int tid = threadIdx.x;
    if (tid < KS * KS) {
        float m = 0.f;
        #pragma unroll
        for (int i = 0; i < KS * KS; ++i) m += noise_eps[i];
        m *= (1.0f / (KS * KS));
        wf[tid] = weight[tid] + noise[0] * (noise_eps[tid] - m);
    }
}

// LDS-free depthwise 7x7: ring-8 fp32 accumulators; one aligned float4 load
// per step prefetched 3 ahead; horizontal halo via DPP wave shifts; dead
// warmup/tail FMAs trimmed at compile time (JLO/JHI); non-temporal stores.
__global__ __launch_bounds__(256) void GaussianConvBlur_conv(
        const float* __restrict__ in,
        const float* __restrict__ wfg,
        float* __restrict__ out) {
    const int lane = threadIdx.x & 63;
    const int wid  = threadIdx.x >> 6;

    const int plane = blockIdx.x;               // 1 block per plane
    const int s0    = __builtin_amdgcn_readfirstlane(wid * STRIP);

    const float* __restrict__ src = in  + (size_t)plane * (H * W);
    float*       __restrict__ dst = out + (size_t)plane * (H * W);

    // Pin the 49 uniform weights to SGPRs
    float wf[KS * KS];
    #pragma unroll
    for (int i = 0; i < KS * KS; ++i)
        wf[i] = __int_as_float(__builtin_amdgcn_readfirstlane(__float_as_int(wfg[i])));

    const int x4 = lane << 2;                   // aligned offset (floats)

    vf4 acc[8];
    #pragma unroll
    for (int i = 0; i < 8; ++i) acc[i] = (vf4)(0.f);

    vf4 pm[4];                                  // depth-3 prefetch ring

    #define LOADROW(REL, P) do {                                          \
        int ri_  = s0 - 3 + (REL);                                        \
        int ric_ = ri_ < 0 ? 0 : (ri_ > (H - 1) ? (H - 1) : ri_);         \
        pm[P] = *(const vf4*)(src + ric_ * W + x4);                       \
    } while (0)

    // j in [JLO,JHI]: at step REL only j >= 6-REL and j <= STRIP+5-REL feed
    // outputs this wave owns — trims dead FMAs at the strip boundaries.
    #define STEPBODY(REL, U, PF, JLO, JHI) do {                           \
        if (PF) LOADROW((REL) + 3, ((U) + 3) & 3);                        \
        const int ri = s0 - 3 + (REL);        /* uniform (SGPR) */        \
        if (ri >= 0 && ri < H) {              /* valid row: accumulate */ \
            vf4 r1 = pm[(U) & 3];                                         \
            float s[10];                                                  \
            s[0] = dpp_shr1(r1.y);            /* lane-1, lane0 -> 0 */    \
            s[1] = dpp_shr1(r1.z);                                        \
            s[2] = dpp_shr1(r1.w);                                        \
            s[3] = r1.x; s[4] = r1.y; s[5] = r1.z; s[6] = r1.w;           \
            s[7] = dpp_shl1(r1.x);            /* lane+1, lane63 -> 0 */   \
            s[8] = dpp_shl1(r1.y);                                        \
            s[9] = dpp_shl1(r1.z);                                        \
            _Pragma("unroll")                                             \
            for (int j = (JLO); j <= (JHI); ++j) {                        \
                const int slot = ((U) + j) & 7;    /* compile-time */     \
                const int ky   = 6 - j;                                   \
                _Pragma("unroll")                                         \
                for (int kx = 0; kx < 7; ++kx) {                          \
                    const float wv = wf[ky * 7 + kx];                     \
                    acc[slot].x = fmaf(wv, s[kx],     acc[slot].x);       \
                    acc[slot].y = fmaf(wv, s[kx + 1], acc[slot].y);       \
                    acc[slot].z = fmaf(wv, s[kx + 2], acc[slot].z);       \
                    acc[slot].w = fmaf(wv, s[kx + 3], acc[slot].w);       \
                }                                                         \
            }                                                             \
        }                                                                 \
        const int o = ri - 3;            /* this row completes now */     \
        if (o >= s0)                                                      \
            __builtin_nontemporal_store(acc[(U) & 7],                     \
                                        (vf4*)(dst + o * W + x4));        \
        acc[(U) & 7] = (vf4)(0.f);                                        \
    } while (0)

    LOADROW(0, 0);
    LOADROW(1, 1);
    LOADROW(2, 2);

    // warmup group: rel = 0..7, trim j < 6-rel
    #pragma unroll
    for (int u = 0; u < 8; ++u)
        STEPBODY(u, u, true, (u < 6 ? 6 - u : 0), 6);

    // full groups: rel = 8..63 (7 groups of 8; ring indices stay aligned)
    for (int g = 1; g < 8; ++g) {
        #pragma unroll
        for (int u = 0; u < 8; ++u)
            STEPBODY(g * 8 + u, u, true, 0, 6);
    }

    // tail: rel = 64..69, trim j > 69-rel; last load is rel 69 (at u=2)
    #pragma unroll
    for (int u = 0; u < 6; ++u)
        STEPBODY(64 + u, u, (u < 3), 0, 5 - u);

    #undef LOADROW
    #undef STEPBODY
}

extern "C" void kernel_launch(void* const* d_in, const int* in_sizes, int n_in,
                              void* d_out, int out_size, void* d_ws, size_t ws_size,
                              hipStream_t stream) {
    const float* x         = (const float*)d_in[0];  // (16,64,256,256)
    const float* weight    = (const float*)d_in[1];  // (64,64,7,7)
    const float* noise     = (const float*)d_in[2];  // scalar
    const float* noise_eps = (const float*)d_in[3];  // (7,7)
    float*       out       = (float*)d_out;
    float*       wf        = (float*)d_ws;           // 49 floats scratch

    GaussianConvBlur_wprep<<<1, 64, 0, stream>>>(weight, noise, noise_eps, wf);

    const int planes = 16 * 64;                       // 1024 planes, 1 block each
    GaussianConvBlur_conv<<<planes, 256, 0, stream>>>(x, wf, out);
}

// Round 11
// 95.763 us; speedup vs baseline: 1.3450x; 1.3450x over previous
//
#include <hip/hip_runtime.h>

#define KS    7
#define H     256
#define W     256
#define STRIP 32                 // output rows per wave
#define WPB   4                  // waves per block (block covers 128 rows)
#define NSTEP (STRIP + KS - 1)   // 38 input rows per strip

typedef float vf4 __attribute__((ext_vector_type(4)));

// lane i <- lane i-1 (lane 0 -> 0): wave_shr:1, bound_ctrl=1
__device__ __forceinline__ float dpp_shr1(float x) {
    return __int_as_float(__builtin_amdgcn_mov_dpp(__float_as_int(x), 0x138, 0xf, 0xf, true));
}
// lane i <- lane i+1 (lane 63 -> 0): wave_shl:1, bound_ctrl=1
__device__ __forceinline__ float dpp_shl1(float x) {
    return __int_as_float(__builtin_amdgcn_mov_dpp(__float_as_int(x), 0x130, 0xf, 0xf, true));
}

// Build effective 7x7 kernel: w_eff = mk + noise*(noise_eps - mean(noise_eps))
__global__ void GaussianConvBlur_wprep(const float* __restrict__ weight,
                                       const float* __restrict__ noise,
                                       const float* __restrict__ noise_eps,
                                       float* __restrict__ wf) {
    int tid = threadIdx.x;
    if (tid < KS * KS) {
        float m = 0.f;
        #pragma unroll
        for (int i = 0; i < KS * KS; ++i) m += noise_eps[i];
        m *= (1.0f / (KS * KS));
        wf[tid] = weight[tid] + noise[0] * (noise_eps[tid] - m);
    }
}

// LDS-free depthwise 7x7 (round-9 geometry): ring-8 fp32 accumulators; one
// aligned float4 load per step prefetched 3 ahead; DPP wave-shift halo;
// compile-time JLO/JHI trim of dead warmup/tail FMAs; non-temporal stores.
__global__ __launch_bounds__(256) void GaussianConvBlur_conv(
        const float* __restrict__ in,
        const float* __restrict__ wfg,
        float* __restrict__ out) {
    const int lane = threadIdx.x & 63;
    const int wid  = threadIdx.x >> 6;

    const int plane = blockIdx.x >> 1;          // 2 blocks per plane
    const int sblk  = blockIdx.x & 1;
    const int s0    = __builtin_amdgcn_readfirstlane((sblk * WPB + wid) * STRIP);

    const float* __restrict__ src = in  + (size_t)plane * (H * W);
    float*       __restrict__ dst = out + (size_t)plane * (H * W);

    // Pin the 49 uniform weights to SGPRs
    float wf[KS * KS];
    #pragma unroll
    for (int i = 0; i < KS * KS; ++i)
        wf[i] = __int_as_float(__builtin_amdgcn_readfirstlane(__float_as_int(wfg[i])));

    const int x4 = lane << 2;                   // aligned offset (floats)

    vf4 acc[8];
    #pragma unroll
    for (int i = 0; i < 8; ++i) acc[i] = (vf4)(0.f);

    vf4 pm[4];                                  // depth-3 prefetch ring

    #define LOADROW(REL, P) do {                                          \
        int ri_  = s0 - 3 + (REL);                                        \
        int ric_ = ri_ < 0 ? 0 : (ri_ > (H - 1) ? (H - 1) : ri_);         \
        pm[P] = *(const vf4*)(src + ric_ * W + x4);                       \
    } while (0)

    // j in [JLO,JHI]: at step REL only j >= 6-REL and j <= STRIP+5-REL feed
    // outputs this wave owns — trims dead FMAs at the strip boundaries.
    #define STEPBODY(REL, U, PF, JLO, JHI) do {                           \
        if (PF) LOADROW((REL) + 3, ((U) + 3) & 3);                        \
        const int ri = s0 - 3 + (REL);        /* uniform (SGPR) */        \
        if (ri >= 0 && ri < H) {              /* valid row: accumulate */ \
            vf4 r1 = pm[(U) & 3];                                         \
            float s[10];                                                  \
            s[0] = dpp_shr1(r1.y);            /* lane-1, lane0 -> 0 */    \
            s[1] = dpp_shr1(r1.z);                                        \
            s[2] = dpp_shr1(r1.w);                                        \
            s[3] = r1.x; s[4] = r1.y; s[5] = r1.z; s[6] = r1.w;           \
            s[7] = dpp_shl1(r1.x);            /* lane+1, lane63 -> 0 */   \
            s[8] = dpp_shl1(r1.y);                                        \
            s[9] = dpp_shl1(r1.z);                                        \
            _Pragma("unroll")                                             \
            for (int j = (JLO); j <= (JHI); ++j) {                        \
                const int slot = ((U) + j) & 7;    /* compile-time */     \
                const int ky   = 6 - j;                                   \
                _Pragma("unroll")                                         \
                for (int kx = 0; kx < 7; ++kx) {                          \
                    const float wv = wf[ky * 7 + kx];                     \
                    acc[slot].x = fmaf(wv, s[kx],     acc[slot].x);       \
                    acc[slot].y = fmaf(wv, s[kx + 1], acc[slot].y);       \
                    acc[slot].z = fmaf(wv, s[kx + 2], acc[slot].z);       \
                    acc[slot].w = fmaf(wv, s[kx + 3], acc[slot].w);       \
                }                                                         \
            }                                                             \
        }                                                                 \
        const int o = ri - 3;            /* this row completes now */     \
        if (o >= s0)                                                      \
            __builtin_nontemporal_store(acc[(U) & 7],                     \
                                        (vf4*)(dst + o * W + x4));        \
        acc[(U) & 7] = (vf4)(0.f);                                        \
    } while (0)

    LOADROW(0, 0);
    LOADROW(1, 1);
    LOADROW(2, 2);

    // warmup group: rel = 0..7, trim j < 6-rel
    #pragma unroll
    for (int u = 0; u < 8; ++u)
        STEPBODY(u, u, true, (u < 6 ? 6 - u : 0), 6);

    // full groups: rel = 8..31 (3 groups of 8; ring indices stay aligned)
    for (int g = 1; g < 4; ++g) {
        #pragma unroll
        for (int u = 0; u < 8; ++u)
            STEPBODY(g * 8 + u, u, true, 0, 6);
    }

    // tail: rel = 32..37, trim j > 37-rel; last load is rel 37 (at u=2)
    #pragma unroll
    for (int u = 0; u < 6; ++u)
        STEPBODY(32 + u, u, (u < 3), 0, 5 - u);

    #undef LOADROW
    #undef STEPBODY
}

extern "C" void kernel_launch(void* const* d_in, const int* in_sizes, int n_in,
                              void* d_out, int out_size, void* d_ws, size_t ws_size,
                              hipStream_t stream) {
    const float* x         = (const float*)d_in[0];  // (16,64,256,256)
    const float* weight    = (const float*)d_in[1];  // (64,64,7,7)
    const float* noise     = (const float*)d_in[2];  // scalar
    const float* noise_eps = (const float*)d_in[3];  // (7,7)
    float*       out       = (float*)d_out;
    float*       wf        = (float*)d_ws;           // 49 floats scratch

    GaussianConvBlur_wprep<<<1, 64, 0, stream>>>(weight, noise, noise_eps, wf);

    const int planes = 16 * 64;                       // 1024 planes
    GaussianConvBlur_conv<<<planes * 2, 256, 0, stream>>>(x, wf, out);
}